// Round 1
// baseline (175.314 us; speedup 1.0000x reference)
//
#include <hip/hip_runtime.h>
#include <math.h>

#define D_MODEL 2048
#define NE      64
#define BM      64
#define KC      32
#define NCH     (D_MODEL / KC)   // 64 k-chunks

// 16 FMAs of a 4x4 outer product into accumulator array A
#define FMA16(A, xa, wb)                                                         \
    A[0][0] += xa.x * wb.x; A[0][1] += xa.x * wb.y;                              \
    A[0][2] += xa.x * wb.z; A[0][3] += xa.x * wb.w;                              \
    A[1][0] += xa.y * wb.x; A[1][1] += xa.y * wb.y;                              \
    A[1][2] += xa.y * wb.z; A[1][3] += xa.y * wb.w;                              \
    A[2][0] += xa.z * wb.x; A[2][1] += xa.z * wb.y;                              \
    A[2][2] += xa.z * wb.z; A[2][3] += xa.z * wb.w;                              \
    A[3][0] += xa.w * wb.x; A[3][1] += xa.w * wb.y;                              \
    A[3][2] += xa.w * wb.z; A[3][3] += xa.w * wb.w;

__global__ __launch_bounds__(256) void router_main_kernel(
    const float* __restrict__ x, const float* __restrict__ W,
    float* __restrict__ out, float* __restrict__ ws_prob,
    float* __restrict__ ws_z, int* __restrict__ ws_cnt, int Ntok)
{
    // transposed staging tiles: sX[k][m] = x[m0+m][k0+k], sW[k][n] = W[n][k0+k]
    // pad 68 floats: b128 reads stay 16B-aligned, banks (4k+4q)%32 -> 2-way (free)
    __shared__ __align__(16) float sX[KC][68];
    __shared__ __align__(16) float sW[KC][68];
    __shared__ float sL[BM][65];            // logits tile, pad 65 for b32 stats reads
    __shared__ float smax[BM], sinv[BM];
    __shared__ float spart[4][NE];
    __shared__ int   hist[NE];

    const int t  = threadIdx.x;
    const int b  = blockIdx.x;
    const int m0 = b * BM;
    const int mq = t & 15;                  // thread's token quad
    const int nq = t >> 4;                  // thread's expert quad

    // staging assignment: slot s in [0,512): row = s>>3, 4-float col group = (s&7)*4
    // lanes 0..7 cover one full 128B row segment -> perfectly coalesced
    const int r1 = t >> 3;                  // rows 0..31
    const int r2 = r1 + 32;                 // rows 32..63
    const int c1 = (t & 7) << 2;

    const float* xp1 = x + (size_t)(m0 + r1) * D_MODEL + c1;
    const float* xp2 = x + (size_t)(m0 + r2) * D_MODEL + c1;
    const float* wp1 = W + (size_t)r1 * D_MODEL + c1;
    const float* wp2 = W + (size_t)r2 * D_MODEL + c1;

    // prefetch chunk 0 into registers
    float4 ax1 = *(const float4*)xp1;
    float4 ax2 = *(const float4*)xp2;
    float4 aw1 = *(const float4*)wp1;
    float4 aw2 = *(const float4*)wp2;

    // two accumulation chains per output (halves chain length -> ~sqrt(2) less
    // rounding error; keeps argmax aligned with the fp32 numpy reference)
    float acc1[4][4] = {};
    float acc2[4][4] = {};

    for (int ch = 0; ch < NCH; ++ch) {
        __syncthreads();                    // previous chunk's compute done
        // reg -> LDS (transpose scatter, b32)
        sX[c1+0][r1] = ax1.x; sX[c1+1][r1] = ax1.y; sX[c1+2][r1] = ax1.z; sX[c1+3][r1] = ax1.w;
        sX[c1+0][r2] = ax2.x; sX[c1+1][r2] = ax2.y; sX[c1+2][r2] = ax2.z; sX[c1+3][r2] = ax2.w;
        sW[c1+0][r1] = aw1.x; sW[c1+1][r1] = aw1.y; sW[c1+2][r1] = aw1.z; sW[c1+3][r1] = aw1.w;
        sW[c1+0][r2] = aw2.x; sW[c1+1][r2] = aw2.y; sW[c1+2][r2] = aw2.z; sW[c1+3][r2] = aw2.w;
        __syncthreads();
        // issue next chunk's global loads; they fly during the compute below
        if (ch + 1 < NCH) {
            xp1 += KC; xp2 += KC; wp1 += KC; wp2 += KC;
            ax1 = *(const float4*)xp1;
            ax2 = *(const float4*)xp2;
            aw1 = *(const float4*)wp1;
            aw2 = *(const float4*)wp2;
        }
        #pragma unroll
        for (int k = 0; k < KC; ++k) {
            float4 xa = *(const float4*)&sX[k][mq << 2];
            float4 wb = *(const float4*)&sW[k][nq << 2];
            if (k < KC / 2) { FMA16(acc1, xa, wb); }
            else            { FMA16(acc2, xa, wb); }
        }
    }

    // ---- fused stats ----
    #pragma unroll
    for (int i = 0; i < 4; ++i)
        #pragma unroll
        for (int j = 0; j < 4; ++j)
            sL[(mq << 2) + i][(nq << 2) + j] = acc1[i][j] + acc2[i][j];
    if (t < NE) hist[t] = 0;
    __syncthreads();

    if (t < BM) {                           // wave 0: one lane per token
        const int m = t;
        float mx = sL[m][0]; int arg = 0;
        #pragma unroll 4
        for (int e = 1; e < NE; ++e) {      // strict > keeps first-max (jnp.argmax)
            float v = sL[m][e];
            if (v > mx) { mx = v; arg = e; }
        }
        float s = 0.f;
        #pragma unroll 4
        for (int e = 0; e < NE; ++e) s += expf(sL[m][e] - mx);
        float inv = 1.f / s;
        out[m0 + m]        = (float)arg;    // expert_index (as f32)
        out[Ntok + m0 + m] = inv;           // expert_prob = exp(mx-mx)/s
        smax[m] = mx; sinv[m] = inv;
        atomicAdd(&hist[arg], 1);           // int LDS atomic: order-independent
        float lse = mx + logf(s);
        float z = lse * lse;
        #pragma unroll
        for (int off = 32; off > 0; off >>= 1) z += __shfl_down(z, off, 64);
        if (t == 0) ws_z[b] = z;
    }
    __syncthreads();

    {   // probsum: all 4 waves, wave mg handles 16 tokens, lane = expert
        const int e = t & 63, mg = t >> 6;
        float p = 0.f;
        #pragma unroll 4
        for (int m = mg * 16; m < mg * 16 + 16; ++m)
            p += expf(sL[m][e] - smax[m]) * sinv[m];
        spart[mg][e] = p;
    }
    __syncthreads();

    if (t < NE) {
        float ps = spart[0][t] + spart[1][t] + spart[2][t] + spart[3][t];
        ws_prob[b * NE + t] = ps;
        ws_cnt[b * NE + t]  = hist[t];
    }
}

__global__ __launch_bounds__(64) void router_final_kernel(
    const float* __restrict__ ws_prob, const float* __restrict__ ws_z,
    const int* __restrict__ ws_cnt, float* __restrict__ out,
    int Ntok, int nblocks)
{
    const int e = threadIdx.x;              // 64 threads = 1 wave
    float ps = 0.f; int c = 0;
    for (int blk = 0; blk < nblocks; ++blk) {   // fixed order: deterministic
        ps += ws_prob[blk * NE + e];
        c  += ws_cnt[blk * NE + e];
    }
    float z = 0.f;
    for (int blk = e; blk < nblocks; blk += 64) z += ws_z[blk];
    #pragma unroll
    for (int off = 32; off > 0; off >>= 1) z += __shfl_down(z, off, 64);

    float fN = (float)Ntok;
    float fp = ((float)c / fN) * (ps / fN); // f_i * p_i
    #pragma unroll
    for (int off = 32; off > 0; off >>= 1) fp += __shfl_down(fp, off, 64);

    out[2 * Ntok + e] = (float)c;           // counts (as f32)
    if (e == 0) {
        int cap = (Ntok + NE - 1) / NE;
        if (cap < 4) cap = 4;
        float zmean = z / fN;
        float aux = 0.01f * (float)NE * fp + 1e-3f * zmean;
        out[2 * Ntok + NE]     = (float)cap; // capacity
        out[2 * Ntok + NE + 1] = aux;        // aux_loss
    }
}

extern "C" void kernel_launch(void* const* d_in, const int* in_sizes, int n_in,
                              void* d_out, int out_size, void* d_ws, size_t ws_size,
                              hipStream_t stream)
{
    const float* x = (const float*)d_in[0];
    const float* W = (const float*)d_in[1];
    float* out = (float*)d_out;

    const int Ntok    = in_sizes[0] / D_MODEL;  // 16384
    const int nblocks = Ntok / BM;              // 256

    float* ws_prob = (float*)d_ws;              // [nblocks][64]
    float* ws_z    = ws_prob + (size_t)nblocks * NE;   // [nblocks]
    int*   ws_cnt  = (int*)(ws_z + nblocks);    // [nblocks][64]

    router_main_kernel<<<nblocks, 256, 0, stream>>>(x, W, out, ws_prob, ws_z, ws_cnt, Ntok);
    router_final_kernel<<<1, 64, 0, stream>>>(ws_prob, ws_z, ws_cnt, out, Ntok, nblocks);
}

// Round 2
// 137.794 us; speedup vs baseline: 1.2723x; 1.2723x over previous
//
#include <hip/hip_runtime.h>
#include <math.h>

#define D_MODEL 2048
#define NE      64
#define BM      64
#define KC      32
#define KS      4
#define KSEG    (D_MODEL / KS)   // 512
#define NCHS    (KSEG / KC)      // 16 chunks per K-segment
#define NCH     (D_MODEL / KC)   // 64 (fallback path)

// 16 FMAs of a 4x4 outer product into accumulator array A
#define FMA16(A, xa, wb)                                                         \
    A[0][0] += xa.x * wb.x; A[0][1] += xa.x * wb.y;                              \
    A[0][2] += xa.x * wb.z; A[0][3] += xa.x * wb.w;                              \
    A[1][0] += xa.y * wb.x; A[1][1] += xa.y * wb.y;                              \
    A[1][2] += xa.y * wb.z; A[1][3] += xa.y * wb.w;                              \
    A[2][0] += xa.z * wb.x; A[2][1] += xa.z * wb.y;                              \
    A[2][2] += xa.z * wb.z; A[2][3] += xa.z * wb.w;                              \
    A[3][0] += xa.w * wb.x; A[3][1] += xa.w * wb.y;                              \
    A[3][2] += xa.w * wb.z; A[3][3] += xa.w * wb.w;

// ---------------- split-K GEMM: partial logits to ws ----------------
// grid (ntiles, KS); block 256. Tile 64 tok x 64 exp over KSEG of K.
// LDS tiles transposed + XOR-swizzled: physical col = row ^ ((k>>2)<<3)
// -> staging writes <=2-way (free), b128 reads stay 16B-aligned, conflict-free.
__global__ __launch_bounds__(256, 4) void router_gemm_kernel(
    const float* __restrict__ x, const float* __restrict__ W,
    float* __restrict__ ws_part, int ntiles)
{
    __shared__ __align__(16) float sX[KC][BM];
    __shared__ __align__(16) float sW[KC][NE];

    const int t    = threadIdx.x;
    const int tile = blockIdx.x;
    const int ks   = blockIdx.y;
    const int m0   = tile * BM;
    const int k0   = ks * KSEG;
    // nq fast (t&15) -> coalesced partial store; mq slow
    const int nq = t & 15;                  // expert quad
    const int mq = t >> 4;                  // token quad
    // staging: rows r1/r2, k-quad c1; swizzled dest column constant per thread
    const int r1 = t >> 3, r2 = r1 + 32;
    const int c1 = (t & 7) << 2;
    const int sw = (t & 7) << 3;            // ((k>>2)&7)<<3 with k=c1+j
    const int col1 = r1 ^ sw, col2 = r2 ^ sw;

    const float* xp1 = x + (size_t)(m0 + r1) * D_MODEL + k0 + c1;
    const float* xp2 = x + (size_t)(m0 + r2) * D_MODEL + k0 + c1;
    const float* wp1 = W + (size_t)r1 * D_MODEL + k0 + c1;
    const float* wp2 = W + (size_t)r2 * D_MODEL + k0 + c1;

    float4 ax1 = *(const float4*)xp1;
    float4 ax2 = *(const float4*)xp2;
    float4 aw1 = *(const float4*)wp1;
    float4 aw2 = *(const float4*)wp2;

    // two accumulation chains (keeps fp32 rounding ~1e-6, argmax-safe)
    float acc1[4][4] = {};
    float acc2[4][4] = {};

    for (int ch = 0; ch < NCHS; ++ch) {
        __syncthreads();
        sX[c1+0][col1] = ax1.x; sX[c1+1][col1] = ax1.y; sX[c1+2][col1] = ax1.z; sX[c1+3][col1] = ax1.w;
        sX[c1+0][col2] = ax2.x; sX[c1+1][col2] = ax2.y; sX[c1+2][col2] = ax2.z; sX[c1+3][col2] = ax2.w;
        sW[c1+0][col1] = aw1.x; sW[c1+1][col1] = aw1.y; sW[c1+2][col1] = aw1.z; sW[c1+3][col1] = aw1.w;
        sW[c1+0][col2] = aw2.x; sW[c1+1][col2] = aw2.y; sW[c1+2][col2] = aw2.z; sW[c1+3][col2] = aw2.w;
        __syncthreads();
        if (ch + 1 < NCHS) {                // next chunk's loads fly during compute
            xp1 += KC; xp2 += KC; wp1 += KC; wp2 += KC;
            ax1 = *(const float4*)xp1;
            ax2 = *(const float4*)xp2;
            aw1 = *(const float4*)wp1;
            aw2 = *(const float4*)wp2;
        }
        #pragma unroll
        for (int k = 0; k < KC; ++k) {
            const int s2 = (k >> 2) << 1;   // swizzle on quad index
            float4 xa = *(const float4*)&sX[k][(mq ^ s2) << 2];
            float4 wb = *(const float4*)&sW[k][(nq ^ s2) << 2];
            if (k < KC / 2) { FMA16(acc1, xa, wb); }
            else            { FMA16(acc2, xa, wb); }
        }
    }

    float* wsp = ws_part + ((size_t)ks * ntiles + tile) * (BM * NE);
    #pragma unroll
    for (int i = 0; i < 4; ++i) {
        float4 v;
        v.x = acc1[i][0] + acc2[i][0];
        v.y = acc1[i][1] + acc2[i][1];
        v.z = acc1[i][2] + acc2[i][2];
        v.w = acc1[i][3] + acc2[i][3];
        *(float4*)&wsp[(mq * 4 + i) * NE + nq * 4] = v;   // 16 consecutive lanes -> 256B
    }
}

// ---------------- reduce partials + fused stats ----------------
__global__ __launch_bounds__(256) void router_stats_kernel(
    const float* __restrict__ ws_part, float* __restrict__ out,
    float* __restrict__ ws_prob, float* __restrict__ ws_z,
    int* __restrict__ ws_cnt, int Ntok, int ntiles)
{
    __shared__ float sL[BM][NE + 1];        // pad 65: conflict-free stats reads
    __shared__ float smax[BM], sinv[BM];
    __shared__ float spart[4][NE];
    __shared__ int   hist[NE];

    const int t  = threadIdx.x;
    const int b  = blockIdx.x;
    const int m0 = b * BM;
    const size_t stride = (size_t)ntiles * BM * NE;
    const float* p = ws_part + (size_t)b * BM * NE;

    #pragma unroll
    for (int r = 0; r < 4; ++r) {           // coalesced f4 reads of 4 partials
        const int q = r * 256 + t;          // f4 index 0..1023
        float4 v0 = *(const float4*)&p[(size_t)q * 4];
        float4 v1 = *(const float4*)&p[(size_t)q * 4 + stride];
        float4 v2 = *(const float4*)&p[(size_t)q * 4 + 2 * stride];
        float4 v3 = *(const float4*)&p[(size_t)q * 4 + 3 * stride];
        float s0 = ((v0.x + v1.x) + v2.x) + v3.x;
        float s1 = ((v0.y + v1.y) + v2.y) + v3.y;
        float s2 = ((v0.z + v1.z) + v2.z) + v3.z;
        float s3 = ((v0.w + v1.w) + v2.w) + v3.w;
        const int row = q >> 4, col = (q & 15) << 2;
        sL[row][col + 0] = s0; sL[row][col + 1] = s1;
        sL[row][col + 2] = s2; sL[row][col + 3] = s3;
    }
    if (t < NE) hist[t] = 0;
    __syncthreads();

    if (t < BM) {                           // wave 0: one lane per token
        const int m = t;
        float mx = sL[m][0]; int arg = 0;
        #pragma unroll 4
        for (int e = 1; e < NE; ++e) {      // strict > : first-max like jnp.argmax
            float v = sL[m][e];
            if (v > mx) { mx = v; arg = e; }
        }
        float s = 0.f;
        #pragma unroll 4
        for (int e = 0; e < NE; ++e) s += expf(sL[m][e] - mx);
        float inv = 1.f / s;
        out[m0 + m]        = (float)arg;    // expert_index
        out[Ntok + m0 + m] = inv;           // expert_prob
        smax[m] = mx; sinv[m] = inv;
        atomicAdd(&hist[arg], 1);
        float lse = mx + logf(s);
        float z = lse * lse;
        #pragma unroll
        for (int off = 32; off > 0; off >>= 1) z += __shfl_down(z, off, 64);
        if (t == 0) ws_z[b] = z;
    }
    __syncthreads();

    {   // probsum: wave mg handles 16 tokens, lane = expert
        const int e = t & 63, mg = t >> 6;
        float pa = 0.f;
        #pragma unroll 4
        for (int m = mg * 16; m < mg * 16 + 16; ++m)
            pa += expf(sL[m][e] - smax[m]) * sinv[m];
        spart[mg][e] = pa;
    }
    __syncthreads();

    if (t < NE) {
        ws_prob[b * NE + t] = spart[0][t] + spart[1][t] + spart[2][t] + spart[3][t];
        ws_cnt[b * NE + t]  = hist[t];
    }
}

__global__ __launch_bounds__(64) void router_final_kernel(
    const float* __restrict__ ws_prob, const float* __restrict__ ws_z,
    const int* __restrict__ ws_cnt, float* __restrict__ out,
    int Ntok, int nblocks)
{
    const int e = threadIdx.x;
    float ps = 0.f; int c = 0;
    for (int blk = 0; blk < nblocks; ++blk) {   // fixed order: deterministic
        ps += ws_prob[blk * NE + e];
        c  += ws_cnt[blk * NE + e];
    }
    float z = 0.f;
    for (int blk = e; blk < nblocks; blk += 64) z += ws_z[blk];
    #pragma unroll
    for (int off = 32; off > 0; off >>= 1) z += __shfl_down(z, off, 64);

    float fN = (float)Ntok;
    float fp = ((float)c / fN) * (ps / fN);
    #pragma unroll
    for (int off = 32; off > 0; off >>= 1) fp += __shfl_down(fp, off, 64);

    out[2 * Ntok + e] = (float)c;
    if (e == 0) {
        int cap = (Ntok + NE - 1) / NE;
        if (cap < 4) cap = 4;
        float aux = 0.01f * (float)NE * fp + 1e-3f * (z / fN);
        out[2 * Ntok + NE]     = (float)cap;
        out[2 * Ntok + NE + 1] = aux;
    }
}

// ---------------- fallback (round-1 proven path, used only if ws too small) ----
__global__ __launch_bounds__(256) void router_main_fb(
    const float* __restrict__ x, const float* __restrict__ W,
    float* __restrict__ out, float* __restrict__ ws_prob,
    float* __restrict__ ws_z, int* __restrict__ ws_cnt, int Ntok)
{
    __shared__ __align__(16) float sX[KC][68];
    __shared__ __align__(16) float sW[KC][68];
    __shared__ float sL[BM][65];
    __shared__ float smax[BM], sinv[BM];
    __shared__ float spart[4][NE];
    __shared__ int   hist[NE];

    const int t = threadIdx.x, b = blockIdx.x, m0 = b * BM;
    const int mq = t & 15, nq = t >> 4;
    const int r1 = t >> 3, r2 = r1 + 32, c1 = (t & 7) << 2;
    const float* xp1 = x + (size_t)(m0 + r1) * D_MODEL + c1;
    const float* xp2 = x + (size_t)(m0 + r2) * D_MODEL + c1;
    const float* wp1 = W + (size_t)r1 * D_MODEL + c1;
    const float* wp2 = W + (size_t)r2 * D_MODEL + c1;
    float4 ax1 = *(const float4*)xp1, ax2 = *(const float4*)xp2;
    float4 aw1 = *(const float4*)wp1, aw2 = *(const float4*)wp2;
    float acc1[4][4] = {}, acc2[4][4] = {};
    for (int ch = 0; ch < NCH; ++ch) {
        __syncthreads();
        sX[c1+0][r1] = ax1.x; sX[c1+1][r1] = ax1.y; sX[c1+2][r1] = ax1.z; sX[c1+3][r1] = ax1.w;
        sX[c1+0][r2] = ax2.x; sX[c1+1][r2] = ax2.y; sX[c1+2][r2] = ax2.z; sX[c1+3][r2] = ax2.w;
        sW[c1+0][r1] = aw1.x; sW[c1+1][r1] = aw1.y; sW[c1+2][r1] = aw1.z; sW[c1+3][r1] = aw1.w;
        sW[c1+0][r2] = aw2.x; sW[c1+1][r2] = aw2.y; sW[c1+2][r2] = aw2.z; sW[c1+3][r2] = aw2.w;
        __syncthreads();
        if (ch + 1 < NCH) {
            xp1 += KC; xp2 += KC; wp1 += KC; wp2 += KC;
            ax1 = *(const float4*)xp1; ax2 = *(const float4*)xp2;
            aw1 = *(const float4*)wp1; aw2 = *(const float4*)wp2;
        }
        #pragma unroll
        for (int k = 0; k < KC; ++k) {
            float4 xa = *(const float4*)&sX[k][mq << 2];
            float4 wb = *(const float4*)&sW[k][nq << 2];
            if (k < KC / 2) { FMA16(acc1, xa, wb); }
            else            { FMA16(acc2, xa, wb); }
        }
    }
    #pragma unroll
    for (int i = 0; i < 4; ++i)
        #pragma unroll
        for (int j = 0; j < 4; ++j)
            sL[(mq << 2) + i][(nq << 2) + j] = acc1[i][j] + acc2[i][j];
    if (t < NE) hist[t] = 0;
    __syncthreads();
    if (t < BM) {
        const int m = t;
        float mx = sL[m][0]; int arg = 0;
        for (int e = 1; e < NE; ++e) { float v = sL[m][e]; if (v > mx) { mx = v; arg = e; } }
        float s = 0.f;
        for (int e = 0; e < NE; ++e) s += expf(sL[m][e] - mx);
        float inv = 1.f / s;
        out[m0 + m] = (float)arg; out[Ntok + m0 + m] = inv;
        smax[m] = mx; sinv[m] = inv;
        atomicAdd(&hist[arg], 1);
        float lse = mx + logf(s); float z = lse * lse;
        for (int off = 32; off > 0; off >>= 1) z += __shfl_down(z, off, 64);
        if (t == 0) ws_z[b] = z;
    }
    __syncthreads();
    {
        const int e = t & 63, mg = t >> 6;
        float pa = 0.f;
        for (int m = mg * 16; m < mg * 16 + 16; ++m) pa += expf(sL[m][e] - smax[m]) * sinv[m];
        spart[mg][e] = pa;
    }
    __syncthreads();
    if (t < NE) {
        ws_prob[b * NE + t] = spart[0][t] + spart[1][t] + spart[2][t] + spart[3][t];
        ws_cnt[b * NE + t]  = hist[t];
    }
}

extern "C" void kernel_launch(void* const* d_in, const int* in_sizes, int n_in,
                              void* d_out, int out_size, void* d_ws, size_t ws_size,
                              hipStream_t stream)
{
    const float* x = (const float*)d_in[0];
    const float* W = (const float*)d_in[1];
    float* out = (float*)d_out;

    const int Ntok   = in_sizes[0] / D_MODEL;   // 16384
    const int ntiles = Ntok / BM;               // 256

    const size_t part_elems = (size_t)KS * ntiles * BM * NE;     // 4M floats
    const size_t need = (part_elems + (size_t)ntiles * NE + ntiles) * 4
                      + (size_t)ntiles * NE * 4 + 1024;

    if (ws_size >= need) {
        float* ws_part = (float*)d_ws;
        float* ws_prob = ws_part + part_elems;
        float* ws_z    = ws_prob + (size_t)ntiles * NE;
        int*   ws_cnt  = (int*)(ws_z + ntiles);

        dim3 grid(ntiles, KS);
        router_gemm_kernel<<<grid, 256, 0, stream>>>(x, W, ws_part, ntiles);
        router_stats_kernel<<<ntiles, 256, 0, stream>>>(ws_part, out, ws_prob, ws_z, ws_cnt, Ntok, ntiles);
        router_final_kernel<<<1, 64, 0, stream>>>(ws_prob, ws_z, ws_cnt, out, Ntok, ntiles);
    } else {
        float* ws_prob = (float*)d_ws;
        float* ws_z    = ws_prob + (size_t)ntiles * NE;
        int*   ws_cnt  = (int*)(ws_z + ntiles);
        router_main_fb<<<ntiles, 256, 0, stream>>>(x, W, out, ws_prob, ws_z, ws_cnt, Ntok);
        router_final_kernel<<<1, 64, 0, stream>>>(ws_prob, ws_z, ws_cnt, out, Ntok, ntiles);
    }
}